// Round 4
// baseline (362.191 us; speedup 1.0000x reference)
//
#include <hip/hip_runtime.h>
#include <hip/hip_bf16.h>

#define CC 64
#define NN 9216
#define NB 2
#define NQT 288            // NN/32 q-tiles per batch
#define NKT 144            // NN/64 kv tiles
#define L2E 1.4426950408889634f

typedef __attribute__((ext_vector_type(4))) float f32x4;
typedef __attribute__((ext_vector_type(8))) short bf16x8;
typedef __attribute__((ext_vector_type(4))) short bf16x4;

static __device__ __forceinline__ short f2bf(float f) {
    union { float f; unsigned u; } a; a.f = f;
    unsigned r = a.u + 0x7FFFu + ((a.u >> 16) & 1u);
    return (short)(r >> 16);
}

// packed f32x2 -> bf16x2 (RNE), single instruction (guide T12 recipe, m240)
static __device__ __forceinline__ unsigned cvtpk(float lo, float hi) {
    unsigned r;
    asm("v_cvt_pk_bf16_f32 %0, %1, %2" : "=v"(r) : "v"(lo), "v"(hi));
    return r;
}

// K=16 bf16 MFMA via BUILTIN (compiler enforces D/A/B non-overlap + hazard nops).
static __device__ __forceinline__ f32x4 mfma16(bf16x4 a, bf16x4 b, f32x4 c) {
#if __has_builtin(__builtin_amdgcn_mfma_f32_16x16x16bf16_1k)
    return __builtin_amdgcn_mfma_f32_16x16x16bf16_1k(a, b, c, 0, 0, 0);
#elif __has_builtin(__builtin_amdgcn_mfma_f32_16x16x16_bf16)
    return __builtin_amdgcn_mfma_f32_16x16x16_bf16(a, b, c, 0, 0, 0);
#else
    // asm fallback, padded with wait-state nops (should not be reached)
    asm volatile("s_nop 1\n\tv_mfma_f32_16x16x16_bf16 %0, %1, %2, %0\n\ts_nop 7"
                 : "+v"(c) : "v"(a), "v"(b));
    return c;
#endif
}

static __device__ __forceinline__ float ex2(float x) {
#if __has_builtin(__builtin_amdgcn_exp2f)
    return __builtin_amdgcn_exp2f(x);
#else
    return exp2f(x);
#endif
}

// ---------------------------------------------------------------------------
// Kernel 1: fused Q/K/V 1x1-conv projections (LDS-staged weights).
//   x [B][C][N] f32 -> Q [B][N][C] bf16, K [B][N][C] bf16, V [B][C][N] bf16
// ---------------------------------------------------------------------------
__global__ __launch_bounds__(256) void proj_kernel(
    const float* __restrict__ x,
    const float* __restrict__ gw, const float* __restrict__ gb,
    const float* __restrict__ tw, const float* __restrict__ tb,
    const float* __restrict__ pw, const float* __restrict__ pb,
    short* __restrict__ Qw, short* __restrict__ Kw, short* __restrict__ Vw)
{
    __shared__ float xs[64][68];
    __shared__ float wsm[3][64][64];
    __shared__ float bsm[3][64];
    const int b  = blockIdx.x / (NN / 64);
    const int n0 = (blockIdx.x % (NN / 64)) * 64;
    const int t  = threadIdx.x;

    float* wf = &wsm[0][0][0];
    for (int i = t; i < 4096; i += 256) {
        wf[i]        = gw[i];
        wf[4096 + i] = tw[i];
        wf[8192 + i] = pw[i];
    }
    if (t < 64) { bsm[0][t] = gb[t]; bsm[1][t] = tb[t]; bsm[2][t] = pb[t]; }

    {   // stage x tile: 64 channels x 64 spatial
        const int c = t >> 2, q = t & 3;
        const float* src = x + ((size_t)b * CC + c) * NN + n0 + q * 16;
        #pragma unroll
        for (int i = 0; i < 4; ++i) {
            float4 v = ((const float4*)src)[i];
            xs[c][q * 16 + i * 4 + 0] = v.x;
            xs[c][q * 16 + i * 4 + 1] = v.y;
            xs[c][q * 16 + i * 4 + 2] = v.z;
            xs[c][q * 16 + i * 4 + 3] = v.w;
        }
    }
    __syncthreads();

    const int n  = t & 63;
    const int og = t >> 6;
    float xr[64];
    #pragma unroll
    for (int c = 0; c < 64; ++c) xr[c] = xs[c][n];

    bf16x8 qv0, qv1, kv0, kv1;
    for (int oi = 0; oi < 16; ++oi) {
        const int o = og * 16 + oi;
        float a0 = bsm[0][o], a1 = bsm[1][o], a2 = bsm[2][o];
        #pragma unroll
        for (int c = 0; c < 64; ++c) {
            const float xv = xr[c];
            a0 += wsm[0][o][c] * xv;
            a1 += wsm[1][o][c] * xv;
            a2 += wsm[2][o][c] * xv;
        }
        Vw[((size_t)b * CC + o) * NN + n0 + n] = f2bf(a0);
        if (oi < 8) { qv0[oi] = f2bf(a1); kv0[oi] = f2bf(a2); }
        else        { qv1[oi - 8] = f2bf(a1); kv1[oi - 8] = f2bf(a2); }
    }
    const size_t qkbase = ((size_t)b * NN + n0 + n) * CC + og * 16;
    *(bf16x8*)&Qw[qkbase]     = qv0;
    *(bf16x8*)&Qw[qkbase + 8] = qv1;
    *(bf16x8*)&Kw[qkbase]     = kv0;
    *(bf16x8*)&Kw[qkbase + 8] = kv1;
}

// ---------------------------------------------------------------------------
// Kernel 2: flash attention, LDS-free / shuffle-free PV.
//   Swapped QK^T (K=32): lane holds S[i=lr][j=jb+tt*16+lg*4+r].
//   That register layout IS the B-operand of mfma_f32_16x16x16_bf16
//   (k=lg*4+e, col=lr) -> PV feeds directly from softmax regs.
//   A-operand = V^T fragments: Vw[c][j], 8B loads.
//   KV-split over SP chunks; partials Yp [SP][B][N][C] f32, Mp/Sp [SP][B][N].
// ---------------------------------------------------------------------------
template<int SP>
__global__ __launch_bounds__(256) void attn_kernel(
    const short* __restrict__ Qw, const short* __restrict__ Kw,
    const short* __restrict__ Vw, float* __restrict__ Yp,
    float* __restrict__ Mp, float* __restrict__ Sp)
{
    constexpr int KCH = NKT / SP;
    const int gw  = blockIdx.x * 4 + (threadIdx.x >> 6);
    const int l   = threadIdx.x & 63;
    const int lr  = l & 15, lg = l >> 4;
    const int qt  = gw % NQT;
    const int rem = gw / NQT;
    const int b   = rem & 1;
    const int sp  = rem >> 1;
    const int q0  = qt * 32;

    const short* Qb = Qw + (size_t)b * NN * CC;
    const short* Kb = Kw + (size_t)b * NN * CC;
    const short* Vb = Vw + (size_t)b * CC * NN;

    bf16x8 qf[2][2];
    #pragma unroll
    for (int qg = 0; qg < 2; ++qg)
        #pragma unroll
        for (int ch = 0; ch < 2; ++ch)
            qf[qg][ch] = *(const bf16x8*)(Qb + (size_t)(q0 + qg * 16 + lr) * CC + ch * 32 + lg * 8);

    f32x4 yacc[2][4];
    #pragma unroll
    for (int qg = 0; qg < 2; ++qg)
        #pragma unroll
        for (int u = 0; u < 4; ++u) yacc[qg][u] = (f32x4){0.f, 0.f, 0.f, 0.f};
    float m[2]  = {-1e30f, -1e30f};
    float ml[2] = {-1e30f * L2E, -1e30f * L2E};
    float se[2] = {0.f, 0.f};

    #pragma unroll 1
    for (int kt = sp * KCH; kt < sp * KCH + KCH; ++kt) {
        const int jb = kt * 64;
        bf16x8 kf[4][2];
        bf16x4 vA[4][4];          // [u = c-tile][tt = j-subtile]
        #pragma unroll
        for (int tt = 0; tt < 4; ++tt)
            #pragma unroll
            for (int ch = 0; ch < 2; ++ch)
                kf[tt][ch] = *(const bf16x8*)(Kb + (jb + tt * 16 + lr) * CC + ch * 32 + lg * 8);
        #pragma unroll
        for (int u = 0; u < 4; ++u)
            #pragma unroll
            for (int tt = 0; tt < 4; ++tt)
                vA[u][tt] = *(const bf16x4*)(Vb + (u * 16 + lr) * NN + jb + tt * 16 + lg * 4);

        #pragma unroll
        for (int qg = 0; qg < 2; ++qg) {
            // S^T tiles: lane holds S[i=q0+qg*16+lr][j=jb+tt*16+lg*4+r]
            f32x4 sv[4];
            #pragma unroll
            for (int tt = 0; tt < 4; ++tt) {
                f32x4 a = (f32x4){0.f, 0.f, 0.f, 0.f};
                a = __builtin_amdgcn_mfma_f32_16x16x32_bf16(kf[tt][0], qf[qg][0], a, 0, 0, 0);
                a = __builtin_amdgcn_mfma_f32_16x16x32_bf16(kf[tt][1], qf[qg][1], a, 0, 0, 0);
                sv[tt] = a;
            }
            // row max (row i=lr lives in 4 lanes: xor 16, 32)
            float mx = -1e30f;
            #pragma unroll
            for (int tt = 0; tt < 4; ++tt)
                #pragma unroll
                for (int r = 0; r < 4; ++r) mx = fmaxf(mx, sv[tt][r]);
            mx = fmaxf(mx, __shfl_xor(mx, 16));
            mx = fmaxf(mx, __shfl_xor(mx, 32));

            // defer-max (T13): only rescale when max grew by > 8
            if (__any(mx > m[qg] + 8.f)) {
                const float mnew  = fmaxf(m[qg], mx);
                const float mlnew = mnew * L2E;
                const float scal  = ex2(ml[qg] - mlnew);
                m[qg]  = mnew;
                ml[qg] = mlnew;
                se[qg] *= scal;
                #pragma unroll
                for (int u = 0; u < 4; ++u) yacc[qg][u] *= scal;
            }

            // P = exp2(s*log2e - ml); pack straight into PV B-fragments
            const float nml = -ml[qg];
            float rs = 0.f;
            bf16x4 pbf[4];
            #pragma unroll
            for (int tt = 0; tt < 4; ++tt) {
                const float p0 = ex2(__builtin_fmaf(sv[tt][0], L2E, nml));
                const float p1 = ex2(__builtin_fmaf(sv[tt][1], L2E, nml));
                const float p2 = ex2(__builtin_fmaf(sv[tt][2], L2E, nml));
                const float p3 = ex2(__builtin_fmaf(sv[tt][3], L2E, nml));
                rs += (p0 + p1) + (p2 + p3);
                union { unsigned u[2]; bf16x4 v; } pk;
                pk.u[0] = cvtpk(p0, p1);
                pk.u[1] = cvtpk(p2, p3);
                pbf[tt] = pk.v;
            }
            rs += __shfl_xor(rs, 16);
            rs += __shfl_xor(rs, 32);
            se[qg] += rs;

            // Y^T += V^T * P^T, K=16 per j-subtile, zero shuffles
            #pragma unroll
            for (int tt = 0; tt < 4; ++tt)
                #pragma unroll
                for (int u = 0; u < 4; ++u)
                    yacc[qg][u] = mfma16(vA[u][tt], pbf[tt], yacc[qg][u]);
        }
    }

    // write partials: yacc holds Y^T[c=u*16+lg*4+r][i=lr] (unnormalized)
    const size_t pbase = (size_t)(sp * NB + b) * NN;
    #pragma unroll
    for (int qg = 0; qg < 2; ++qg) {
        const int n = q0 + qg * 16 + lr;
        float* yrow = Yp + (pbase + n) * CC;
        #pragma unroll
        for (int u = 0; u < 4; ++u)
            *(f32x4*)&yrow[u * 16 + lg * 4] = yacc[qg][u];
        if (lg == 0) { Mp[pbase + n] = m[qg]; Sp[pbase + n] = se[qg]; }
    }
}

// ---------------------------------------------------------------------------
// Kernel 3: merge KV-split partials + W conv (LDS weights) + BN + residual.
// ---------------------------------------------------------------------------
template<int SP>
__global__ __launch_bounds__(256) void out_kernel(
    const float* __restrict__ Yp, const float* __restrict__ Mp,
    const float* __restrict__ Sp, const float* __restrict__ x,
    const float* __restrict__ ww, const float* __restrict__ wb,
    const float* __restrict__ gam, const float* __restrict__ bet,
    const float* __restrict__ mu, const float* __restrict__ var,
    float* __restrict__ out)
{
    __shared__ float ys[64][65];
    __shared__ float wsm[64][64];
    __shared__ float wgt[SP][64];
    __shared__ float scl[64], shf[64];
    const int b  = blockIdx.x / (NN / 64);
    const int n0 = (blockIdx.x % (NN / 64)) * 64;
    const int t  = threadIdx.x;

    float* wf = &wsm[0][0];
    for (int i = t; i < 4096; i += 256) wf[i] = ww[i];
    if (t < 64) {
        float e[SP], ssv[SP];
        float M = -1e30f;
        #pragma unroll
        for (int s = 0; s < SP; ++s) {
            e[s]   = Mp[(size_t)(s * NB + b) * NN + n0 + t];
            ssv[s] = Sp[(size_t)(s * NB + b) * NN + n0 + t];
            M = fmaxf(M, e[s]);
        }
        float den = 0.f;
        #pragma unroll
        for (int s = 0; s < SP; ++s) { e[s] = __expf(e[s] - M); den += e[s] * ssv[s]; }
        const float inv = 1.f / den;
        #pragma unroll
        for (int s = 0; s < SP; ++s) wgt[s][t] = e[s] * inv;
    } else if (t < 128) {
        const int c = t - 64;
        const float sc = gam[c] * rsqrtf(var[c] + 1e-5f);
        scl[c] = sc;
        shf[c] = bet[c] + (wb[c] - mu[c]) * sc;
    }
    __syncthreads();

    {   // merge-stage y tile [n][c]
        const int n = t >> 2, q = t & 3;
        float acc[16];
        #pragma unroll
        for (int i = 0; i < 16; ++i) acc[i] = 0.f;
        #pragma unroll
        for (int s = 0; s < SP; ++s) {
            const float w = wgt[s][n];
            const float* src = Yp + ((size_t)(s * NB + b) * NN + n0 + n) * CC + q * 16;
            #pragma unroll
            for (int i = 0; i < 4; ++i) {
                const float4 v = ((const float4*)src)[i];
                acc[i * 4 + 0] += w * v.x;
                acc[i * 4 + 1] += w * v.y;
                acc[i * 4 + 2] += w * v.z;
                acc[i * 4 + 3] += w * v.w;
            }
        }
        #pragma unroll
        for (int i = 0; i < 16; ++i) ys[n][q * 16 + i] = acc[i];
    }
    __syncthreads();

    const int n  = t & 63;
    const int og = t >> 6;
    float yr[64];
    #pragma unroll
    for (int c = 0; c < 64; ++c) yr[c] = ys[n][c];

    for (int oi = 0; oi < 16; ++oi) {
        const int o = og * 16 + oi;
        float a0 = 0.f, a1 = 0.f;
        #pragma unroll
        for (int c = 0; c < 64; c += 2) {
            a0 += wsm[o][c]     * yr[c];
            a1 += wsm[o][c + 1] * yr[c + 1];
        }
        const size_t oidx = ((size_t)b * CC + o) * NN + n0 + n;
        out[oidx] = (a0 + a1) * scl[o] + shf[o] + x[oidx];
    }
}

// ---------------------------------------------------------------------------
extern "C" void kernel_launch(void* const* d_in, const int* in_sizes, int n_in,
                              void* d_out, int out_size, void* d_ws, size_t ws_size,
                              hipStream_t stream) {
    const float* x    = (const float*)d_in[0];
    const float* g_w  = (const float*)d_in[1];
    const float* g_b  = (const float*)d_in[2];
    const float* th_w = (const float*)d_in[3];
    const float* th_b = (const float*)d_in[4];
    const float* ph_w = (const float*)d_in[5];
    const float* ph_b = (const float*)d_in[6];
    const float* w_w  = (const float*)d_in[7];
    const float* w_b  = (const float*)d_in[8];
    const float* bn_g = (const float*)d_in[9];
    const float* bn_b = (const float*)d_in[10];
    const float* bn_m = (const float*)d_in[11];
    const float* bn_v = (const float*)d_in[12];
    float* out = (float*)d_out;

    // ws: Q | K | V bf16 (2.36 MB each) | Yp f32 [SP][B][N][C] | Mp | Sp
    char* wsp = (char*)d_ws;
    short* Qw = (short*)(wsp);
    short* Kw = (short*)(wsp + 2359296);
    short* Vw = (short*)(wsp + 4718592);
    const size_t ypOff = 7077888;
    const size_t perSplit = 4718592 + 2 * 73728;
    int SP = 1;
    if      (ws_size >= ypOff + 8 * perSplit) SP = 8;
    else if (ws_size >= ypOff + 4 * perSplit) SP = 4;
    else if (ws_size >= ypOff + 2 * perSplit) SP = 2;
    float* Yp = (float*)(wsp + ypOff);
    float* Mp = (float*)(wsp + ypOff + (size_t)SP * 4718592);
    float* Sp = (float*)(wsp + ypOff + (size_t)SP * 4718592 + (size_t)SP * 73728);

    proj_kernel<<<NB * (NN / 64), 256, 0, stream>>>(x, g_w, g_b, th_w, th_b,
                                                    ph_w, ph_b, Qw, Kw, Vw);
    if (SP == 8) {
        attn_kernel<8><<<8 * 144, 256, 0, stream>>>(Qw, Kw, Vw, Yp, Mp, Sp);
        out_kernel<8><<<NB * (NN / 64), 256, 0, stream>>>(Yp, Mp, Sp, x, w_w, w_b,
                                                          bn_g, bn_b, bn_m, bn_v, out);
    } else if (SP == 4) {
        attn_kernel<4><<<4 * 144, 256, 0, stream>>>(Qw, Kw, Vw, Yp, Mp, Sp);
        out_kernel<4><<<NB * (NN / 64), 256, 0, stream>>>(Yp, Mp, Sp, x, w_w, w_b,
                                                          bn_g, bn_b, bn_m, bn_v, out);
    } else if (SP == 2) {
        attn_kernel<2><<<2 * 144, 256, 0, stream>>>(Qw, Kw, Vw, Yp, Mp, Sp);
        out_kernel<2><<<NB * (NN / 64), 256, 0, stream>>>(Yp, Mp, Sp, x, w_w, w_b,
                                                          bn_g, bn_b, bn_m, bn_v, out);
    } else {
        attn_kernel<1><<<1 * 144, 256, 0, stream>>>(Qw, Kw, Vw, Yp, Mp, Sp);
        out_kernel<1><<<NB * (NN / 64), 256, 0, stream>>>(Yp, Mp, Sp, x, w_w, w_b,
                                                          bn_g, bn_b, bn_m, bn_v, out);
    }
}